// Round 6
// baseline (2216.572 us; speedup 1.0000x reference)
//
#include <hip/hip_runtime.h>
#include <math.h>

// ---------------------------------------------------------------------------
// 2-layer GCN forward — bucketed counting-split, ZERO global atomics.
//   Buckets of 512 target nodes (NB = ceil(n/512) <= 1024).
//   k_count      : per-block LDS histogram over buckets -> hist_g (coalesced)
//   scan         : hierarchical exclusive scan (bucket-major) -> scatter bases
//   k_scatter    : LDS cursors; edge_g[pos] = pack{w:32|collow:9|row:19}
//   k_prep       : per-bucket degw (LDS f32 atomics) -> dinv; fused gemm1
//   k_pull16_b   : per-bucket LDS acc[512][17] (PADDED stride 17 — random cl
//                  maps across all 32 banks instead of 2; R5's stride-16 gave
//                  ~32-way LDS-atomic conflicts = the 1351us stall), 512 thr.
//   k_pull2_b    : per-bucket LDS acc[512][3] (padded), log_softmax -> out
// Fallback to the R1 atomic-scatter path if ws too small / n too large.
// ---------------------------------------------------------------------------

typedef unsigned long long u64;
typedef unsigned int u32;

#define BKT    512        // nodes per bucket (collow = 9 bits)
#define NBMAX  1024       // max buckets (=> n <= 2^19, matches row:19 packing)
#define NBLK   512        // partition blocks for count/scatter

// ---------------- count / scan / scatter ----------------

__global__ __launch_bounds__(256) void k_count(const int* __restrict__ col,
                                               u32* __restrict__ hist_g,
                                               int NB, int E, int CH) {
    __shared__ u32 cnt[NBMAX];
    for (int b = threadIdx.x; b < NB; b += 256) cnt[b] = 0;
    __syncthreads();
    int blk = blockIdx.x;
    int s = blk * CH, e = min(s + CH, E);
    for (int i = s + threadIdx.x; i < e; i += 256)
        atomicAdd(&cnt[col[i] >> 9], 1u);          // LDS atomic
    __syncthreads();
    for (int b = threadIdx.x; b < NB; b += 256)
        hist_g[(size_t)blk * NB + b] = cnt[b];     // coalesced
}

// logical index e = bucket*NBLK + blk ; physical = blk*NB + bucket
__global__ __launch_bounds__(256) void k_scan_local32(const u32* __restrict__ hist_g,
                                                      u32* __restrict__ base_g,
                                                      u32* __restrict__ bsum,
                                                      int NB, int M) {
    __shared__ u32 s[256];
    int t = threadIdx.x;
    int e = blockIdx.x * 256 + t;
    u32 v = 0;
    if (e < M) {
        int b = e / NBLK, blk = e % NBLK;
        v = hist_g[(size_t)blk * NB + b];
    }
    s[t] = v;
    __syncthreads();
    for (int off = 1; off < 256; off <<= 1) {
        u32 u = (t >= off) ? s[t - off] : 0;
        __syncthreads();
        s[t] += u;
        __syncthreads();
    }
    if (e < M) base_g[e] = s[t] - v;               // exclusive
    if (t == 255) bsum[blockIdx.x] = s[255];
}

__global__ __launch_bounds__(256) void k_scan_sums32(u32* __restrict__ bsum, int nb) {
    __shared__ u32 s[256];
    __shared__ u32 carry;
    int t = threadIdx.x;
    if (t == 0) carry = 0;
    __syncthreads();
    int chunks = (nb + 255) / 256;
    for (int ch = 0; ch < chunks; ch++) {
        int i = ch * 256 + t;
        u32 v = (i < nb) ? bsum[i] : 0;
        s[t] = v;
        __syncthreads();
        for (int off = 1; off < 256; off <<= 1) {
            u32 u = (t >= off) ? s[t - off] : 0;
            __syncthreads();
            s[t] += u;
            __syncthreads();
        }
        u32 incl = s[t];
        u32 my_carry = carry;
        if (i < nb) bsum[i] = incl - v + my_carry;
        __syncthreads();
        if (t == 0) carry = my_carry + s[255];
        __syncthreads();
    }
}

__global__ __launch_bounds__(256) void k_scan_add32(u32* __restrict__ base_g,
                                                    const u32* __restrict__ bsum,
                                                    int M) {
    int e = blockIdx.x * 256 + threadIdx.x;
    if (e < M) base_g[e] += bsum[blockIdx.x];
}

__global__ __launch_bounds__(256) void k_scatter(const int* __restrict__ row,
                                                 const int* __restrict__ col,
                                                 const float* __restrict__ w,
                                                 const u32* __restrict__ base_g,
                                                 u64* __restrict__ edge_g,
                                                 int NB, int E, int CH) {
    __shared__ u32 cursor[NBMAX];
    int blk = blockIdx.x;
    for (int b = threadIdx.x; b < NB; b += 256)
        cursor[b] = base_g[(size_t)b * NBLK + blk];
    __syncthreads();
    int s = blk * CH, e = min(s + CH, E);
    for (int i = s + threadIdx.x; i < e; i += 256) {
        int c = col[i];
        int b = c >> 9;
        u32 pos = atomicAdd(&cursor[b], 1u);       // LDS atomic
        u64 rec = ((u64)__float_as_uint(w[i]) << 32)
                | ((u64)(u32)(c & 511) << 19) | (u64)(u32)row[i];
        edge_g[pos] = rec;
    }
}

// ---------------- prep: deg -> dinv, fused gemm1 ----------------

__global__ __launch_bounds__(256) void k_prep(const u64* __restrict__ edge_g,
                                              const u32* __restrict__ base_g,
                                              const float* __restrict__ x,
                                              const float* __restrict__ W1,
                                              float* __restrict__ dinv_g,
                                              float* __restrict__ h1s,
                                              int NB, int n, int E) {
    __shared__ float degw[BKT];
    __shared__ float sW[176];
    int b = blockIdx.x;
    for (int j = threadIdx.x; j < BKT; j += 256) degw[j] = 1.0f;  // self-loop
    for (int t = threadIdx.x; t < 176; t += 256) sW[t] = W1[t];
    __syncthreads();
    int s = (int)base_g[(size_t)b * NBLK];
    int e = (b + 1 < NB) ? (int)base_g[(size_t)(b + 1) * NBLK] : E;
    for (int i = s + threadIdx.x; i < e; i += 256) {
        u64 rec = edge_g[i];
        int cl = (int)(((u32)rec >> 19) & 511u);
        float wv = __uint_as_float((u32)(rec >> 32));
        atomicAdd(&degw[cl], wv);                  // LDS f32 atomic
    }
    __syncthreads();
    int node0 = b << 9;
    int nn = min(BKT, n - node0);
    for (int j = threadIdx.x; j < nn; j += 256) {
        int node = node0 + j;
        float dv = rsqrtf(degw[j]);
        dinv_g[node] = dv;
        float xi[11];
#pragma unroll
        for (int k = 0; k < 11; k++) xi[k] = x[(size_t)node * 11 + k];
#pragma unroll
        for (int f = 0; f < 16; f++) {
            float a = 0.f;
#pragma unroll
            for (int k = 0; k < 11; k++) a += xi[k] * sW[k * 16 + f];
            h1s[(size_t)node * 16 + f] = dv * a;
        }
    }
}

// ---------------- bucketed pull layers ----------------

#define AST 17   // padded acc stride: bank = (cl*17+k)%32 covers all 32 banks

__global__ __launch_bounds__(512) void k_pull16_b(const u64* __restrict__ edge_g,
                                                  const u32* __restrict__ base_g,
                                                  const float* __restrict__ h1s,
                                                  const float* __restrict__ dinv_g,
                                                  const float* __restrict__ b1,
                                                  const float* __restrict__ W2,
                                                  float* __restrict__ h2s,
                                                  int NB, int n, int E) {
    __shared__ float acc[BKT * AST];  // 34816 B, 4 blocks/CU, 512thr -> ~32 waves
    __shared__ float sW[32];
    __shared__ float sb[16];
    if (threadIdx.x < 32) sW[threadIdx.x] = W2[threadIdx.x];
    if (threadIdx.x < 16) sb[threadIdx.x] = b1[threadIdx.x];
    int b = blockIdx.x;
    int node0 = b << 9;
    int nn = min(BKT, n - node0);
    for (int t = threadIdx.x; t < nn * 16; t += 512) {
        int j = t >> 4, f = t & 15;
        acc[j * AST + f] = h1s[(size_t)node0 * 16 + t];   // init with self term
    }
    __syncthreads();
    int s = (int)base_g[(size_t)b * NBLK];
    int e = (b + 1 < NB) ? (int)base_g[(size_t)(b + 1) * NBLK] : E;
#pragma unroll 2
    for (int i = s + threadIdx.x; i < e; i += 512) {
        u64 rec = edge_g[i];
        int r  = (int)((u32)rec & 0x7FFFFu);
        int cl = (int)(((u32)rec >> 19) & 511u);
        float wv = __uint_as_float((u32)(rec >> 32));
        const float4* hr = (const float4*)(h1s + (size_t)r * 16);
        float4 h0 = hr[0], h1v = hr[1], h2v = hr[2], h3v = hr[3];
        float* a = acc + cl * AST;
        atomicAdd(a + 0,  wv * h0.x);  atomicAdd(a + 1,  wv * h0.y);
        atomicAdd(a + 2,  wv * h0.z);  atomicAdd(a + 3,  wv * h0.w);
        atomicAdd(a + 4,  wv * h1v.x); atomicAdd(a + 5,  wv * h1v.y);
        atomicAdd(a + 6,  wv * h1v.z); atomicAdd(a + 7,  wv * h1v.w);
        atomicAdd(a + 8,  wv * h2v.x); atomicAdd(a + 9,  wv * h2v.y);
        atomicAdd(a + 10, wv * h2v.z); atomicAdd(a + 11, wv * h2v.w);
        atomicAdd(a + 12, wv * h3v.x); atomicAdd(a + 13, wv * h3v.y);
        atomicAdd(a + 14, wv * h3v.z); atomicAdd(a + 15, wv * h3v.w);
    }
    __syncthreads();
    for (int j = threadIdx.x; j < nn; j += 512) {
        int node = node0 + j;
        float dv = dinv_g[node];
        float o0 = 0.f, o1 = 0.f;
#pragma unroll
        for (int f = 0; f < 16; f++) {
            float hrl = fmaxf(dv * acc[j * AST + f] + sb[f], 0.f);
            o0 += hrl * sW[f * 2 + 0];
            o1 += hrl * sW[f * 2 + 1];
        }
        float2 ov; ov.x = dv * o0; ov.y = dv * o1;  // h2s = dinv * h2
        *(float2*)(h2s + (size_t)node * 2) = ov;
    }
}

#define AST2 3   // padded stride for 2-wide acc

__global__ __launch_bounds__(256) void k_pull2_b(const u64* __restrict__ edge_g,
                                                 const u32* __restrict__ base_g,
                                                 const float* __restrict__ h2s,
                                                 const float* __restrict__ dinv_g,
                                                 const float* __restrict__ b2,
                                                 float* __restrict__ out,
                                                 int NB, int n, int E) {
    __shared__ float acc[BKT * AST2];   // 6 KB
    int b = blockIdx.x;
    int node0 = b << 9;
    int nn = min(BKT, n - node0);
    for (int t = threadIdx.x; t < nn * 2; t += 256) {
        int j = t >> 1, f = t & 1;
        acc[j * AST2 + f] = h2s[(size_t)node0 * 2 + t];   // init with self term
    }
    __syncthreads();
    int s = (int)base_g[(size_t)b * NBLK];
    int e = (b + 1 < NB) ? (int)base_g[(size_t)(b + 1) * NBLK] : E;
#pragma unroll 2
    for (int i = s + threadIdx.x; i < e; i += 256) {
        u64 rec = edge_g[i];
        int r  = (int)((u32)rec & 0x7FFFFu);
        int cl = (int)(((u32)rec >> 19) & 511u);
        float wv = __uint_as_float((u32)(rec >> 32));
        float2 hv = *(const float2*)(h2s + (size_t)r * 2);
        atomicAdd(&acc[cl * AST2 + 0], wv * hv.x);
        atomicAdd(&acc[cl * AST2 + 1], wv * hv.y);
    }
    __syncthreads();
    float c0 = b2[0], c1 = b2[1];
    for (int j = threadIdx.x; j < nn; j += 256) {
        int node = node0 + j;
        float dv = dinv_g[node];
        float v0 = dv * acc[j * AST2 + 0] + c0;
        float v1 = dv * acc[j * AST2 + 1] + c1;
        float m = fmaxf(v0, v1);
        float lse = m + logf(expf(v0 - m) + expf(v1 - m));
        float2 ov; ov.x = v0 - lse; ov.y = v1 - lse;
        *(float2*)(out + (size_t)node * 2) = ov;
    }
}

// ---------------- fallback atomic-scatter kernels (R1 proven path) ----------------

__global__ __launch_bounds__(256) void k_init_deg(float* deg, int n) {
    int i = blockIdx.x * blockDim.x + threadIdx.x;
    if (i < n) deg[i] = 1.0f;
}

__global__ __launch_bounds__(256) void k_deg_accum(const int* __restrict__ col,
                                                   const float* __restrict__ w,
                                                   float* __restrict__ deg, int E) {
    int i = blockIdx.x * blockDim.x + threadIdx.x;
    if (i < E) atomicAdd(&deg[col[i]], w[i]);
}

__global__ __launch_bounds__(256) void k_rsqrt(float* deg, int n) {
    int i = blockIdx.x * blockDim.x + threadIdx.x;
    if (i < n) {
        float d = deg[i];
        deg[i] = (d > 0.0f) ? rsqrtf(d) : 0.0f;
    }
}

__global__ __launch_bounds__(256) void k_gemm1_plain(const float* __restrict__ x,
                                                     const float* __restrict__ W1,
                                                     float* __restrict__ h1, int n) {
    __shared__ float sW[176];
    for (int t = threadIdx.x; t < 176; t += blockDim.x) sW[t] = W1[t];
    __syncthreads();
    int i = blockIdx.x * blockDim.x + threadIdx.x;
    if (i >= n) return;
    float xi[11];
#pragma unroll
    for (int k = 0; k < 11; k++) xi[k] = x[(size_t)i * 11 + k];
#pragma unroll
    for (int f = 0; f < 16; f++) {
        float acc = 0.0f;
#pragma unroll
        for (int k = 0; k < 11; k++) acc += xi[k] * sW[k * 16 + f];
        h1[(size_t)i * 16 + f] = acc;
    }
}

__global__ __launch_bounds__(256) void k_scatter16(const int* __restrict__ row,
                                                   const int* __restrict__ col,
                                                   const float* __restrict__ w,
                                                   const float* __restrict__ dinv,
                                                   const float* __restrict__ h1,
                                                   float* __restrict__ acc, int E) {
    int i = blockIdx.x * blockDim.x + threadIdx.x;
    if (i >= E) return;
    int r = row[i], c = col[i];
    float nw = dinv[r] * w[i] * dinv[c];
    const float4* hr = (const float4*)(h1 + (size_t)r * 16);
    float* o = acc + (size_t)c * 16;
#pragma unroll
    for (int q = 0; q < 4; q++) {
        float4 hv = hr[q];
        atomicAdd(o + q * 4 + 0, nw * hv.x);
        atomicAdd(o + q * 4 + 1, nw * hv.y);
        atomicAdd(o + q * 4 + 2, nw * hv.z);
        atomicAdd(o + q * 4 + 3, nw * hv.w);
    }
}

__global__ __launch_bounds__(256) void k_post1(const float* __restrict__ h1,
                                               const float* __restrict__ dinv,
                                               const float* __restrict__ b1,
                                               float* __restrict__ acc, int n) {
    int i = blockIdx.x * blockDim.x + threadIdx.x;
    if (i >= n) return;
    float dv = dinv[i];
    float cs = dv * dv;
#pragma unroll
    for (int f = 0; f < 16; f++) {
        float v = acc[(size_t)i * 16 + f] + cs * h1[(size_t)i * 16 + f] + b1[f];
        acc[(size_t)i * 16 + f] = v > 0.0f ? v : 0.0f;
    }
}

__global__ __launch_bounds__(256) void k_gemm2(const float* __restrict__ hrelu,
                                               const float* __restrict__ W2,
                                               float* __restrict__ h2, int n) {
    __shared__ float sW[32];
    for (int t = threadIdx.x; t < 32; t += blockDim.x) sW[t] = W2[t];
    __syncthreads();
    int i = blockIdx.x * blockDim.x + threadIdx.x;
    if (i >= n) return;
    float a0 = 0.0f, a1 = 0.0f;
#pragma unroll
    for (int f = 0; f < 16; f++) {
        float h = hrelu[(size_t)i * 16 + f];
        a0 += h * sW[f * 2 + 0];
        a1 += h * sW[f * 2 + 1];
    }
    h2[(size_t)i * 2 + 0] = a0;
    h2[(size_t)i * 2 + 1] = a1;
}

__global__ __launch_bounds__(256) void k_scatter2(const int* __restrict__ row,
                                                  const int* __restrict__ col,
                                                  const float* __restrict__ w,
                                                  const float* __restrict__ dinv,
                                                  const float* __restrict__ h2,
                                                  float* __restrict__ out, int E) {
    int i = blockIdx.x * blockDim.x + threadIdx.x;
    if (i >= E) return;
    int r = row[i], c = col[i];
    float nw = dinv[r] * w[i] * dinv[c];
    atomicAdd(&out[(size_t)c * 2 + 0], nw * h2[(size_t)r * 2 + 0]);
    atomicAdd(&out[(size_t)c * 2 + 1], nw * h2[(size_t)r * 2 + 1]);
}

__global__ __launch_bounds__(256) void k_final(const float* __restrict__ h2,
                                               const float* __restrict__ dinv,
                                               const float* __restrict__ b2,
                                               float* __restrict__ out, int n) {
    int i = blockIdx.x * blockDim.x + threadIdx.x;
    if (i >= n) return;
    float dv = dinv[i];
    float cs = dv * dv;
    float v0 = out[(size_t)i * 2 + 0] + cs * h2[(size_t)i * 2 + 0] + b2[0];
    float v1 = out[(size_t)i * 2 + 1] + cs * h2[(size_t)i * 2 + 1] + b2[1];
    float m = fmaxf(v0, v1);
    float lse = m + logf(expf(v0 - m) + expf(v1 - m));
    out[(size_t)i * 2 + 0] = v0 - lse;
    out[(size_t)i * 2 + 1] = v1 - lse;
}

// ---------------- launch ----------------

static inline size_t align64(size_t x) { return (x + 63) & ~(size_t)63; }

extern "C" void kernel_launch(void* const* d_in, const int* in_sizes, int n_in,
                              void* d_out, int out_size, void* d_ws, size_t ws_size,
                              hipStream_t stream) {
    const float* x  = (const float*)d_in[0];
    const int*   ei = (const int*)d_in[1];
    const float* ew = (const float*)d_in[2];
    const float* W1 = (const float*)d_in[3];
    const float* b1 = (const float*)d_in[4];
    const float* W2 = (const float*)d_in[5];
    const float* b2 = (const float*)d_in[6];

    const int n = in_sizes[0] / 11;
    const int E = in_sizes[2];
    const int* rowp = ei;       // sources
    const int* colp = ei + E;   // targets

    const int TB = 256;
    const int gN = (n + TB - 1) / TB;
    const int gE = (E + TB - 1) / TB;

    const int NB = (n + BKT - 1) / BKT;            // buckets
    const int CH = (E + NBLK - 1) / NBLK;          // edges per partition block
    const int M  = NB * NBLK;                      // scan length
    const int SB = (M + 255) / 256;                // scan blocks

    // --- workspace layout (bucketed path) ---
    char* base = (char*)d_ws;
    size_t o_hist = 0;                                        // u32 M
    size_t o_base = align64(o_hist + (size_t)M * 4);          // u32 M
    size_t o_bsum = align64(o_base + (size_t)M * 4);          // u32 SB
    size_t o_dinv = align64(o_bsum + (size_t)SB * 4);         // f32 n
    size_t o_h1   = align64(o_dinv + (size_t)n * 4);          // f32 16n
    size_t o_h2   = align64(o_h1 + (size_t)n * 16 * 4);       // f32 2n
    size_t o_edge = align64(o_h2 + (size_t)n * 2 * 4);        // u64 E
    size_t needed = align64(o_edge + (size_t)E * 8);

    float* outf = (float*)d_out;

    if (ws_size >= needed && n <= (1 << 19) && NB <= NBMAX) {
        u32*   hist_g = (u32*)(base + o_hist);
        u32*   base_g = (u32*)(base + o_base);
        u32*   bsum   = (u32*)(base + o_bsum);
        float* dinv_g = (float*)(base + o_dinv);
        float* h1s    = (float*)(base + o_h1);
        float* h2s    = (float*)(base + o_h2);
        u64*   edge_g = (u64*)(base + o_edge);

        k_count<<<NBLK, TB, 0, stream>>>(colp, hist_g, NB, E, CH);
        k_scan_local32<<<SB, TB, 0, stream>>>(hist_g, base_g, bsum, NB, M);
        k_scan_sums32<<<1, TB, 0, stream>>>(bsum, SB);
        k_scan_add32<<<SB, TB, 0, stream>>>(base_g, bsum, M);
        k_scatter<<<NBLK, TB, 0, stream>>>(rowp, colp, ew, base_g, edge_g, NB, E, CH);
        k_prep<<<NB, TB, 0, stream>>>(edge_g, base_g, x, W1, dinv_g, h1s, NB, n, E);
        k_pull16_b<<<NB, 512, 0, stream>>>(edge_g, base_g, h1s, dinv_g, b1, W2, h2s, NB, n, E);
        k_pull2_b<<<NB, TB, 0, stream>>>(edge_g, base_g, h2s, dinv_g, b2, outf, NB, n, E);
    } else {
        // fallback: atomic-scatter path (R1)
        float* ws   = (float*)d_ws;
        float* dinv = ws;
        float* h1   = ws + (size_t)n;
        float* acc1 = ws + (size_t)n * 17;

        k_init_deg<<<gN, TB, 0, stream>>>(dinv, n);
        k_deg_accum<<<gE, TB, 0, stream>>>(colp, ew, dinv, E);
        k_rsqrt<<<gN, TB, 0, stream>>>(dinv, n);

        k_gemm1_plain<<<gN, TB, 0, stream>>>(x, W1, h1, n);
        hipMemsetAsync(acc1, 0, (size_t)n * 16 * sizeof(float), stream);
        k_scatter16<<<gE, TB, 0, stream>>>(rowp, colp, ew, dinv, h1, acc1, E);
        k_post1<<<gN, TB, 0, stream>>>(h1, dinv, b1, acc1, n);

        float* h2 = h1;
        k_gemm2<<<gN, TB, 0, stream>>>(acc1, W2, h2, n);
        hipMemsetAsync(outf, 0, (size_t)n * 2 * sizeof(float), stream);
        k_scatter2<<<gE, TB, 0, stream>>>(rowp, colp, ew, dinv, h2, outf, E);
        k_final<<<gN, TB, 0, stream>>>(h2, dinv, b2, outf, n);
    }
}

// Round 7
// 1796.097 us; speedup vs baseline: 1.2341x; 1.2341x over previous
//
#include <hip/hip_runtime.h>
#include <math.h>

// ---------------------------------------------------------------------------
// 2-layer GCN forward — bucketed counting-split, ZERO global atomics.
// R7 key change: aggregation is LINEAR, so layer 1 pulls the RAW 11-dim
// features (fp16, dinv-prescaled, 32B padded rows -> 16MB table) and applies
// W1+b1+relu+W2 in the epilogue. Halves random-gather bytes (64B->32B/edge),
// kills gemm1 and the 32MB h1s table. 4-edge batching deepens MLP.
//   k_count    : per-block LDS histogram over 512-node buckets
//   scan       : exclusive scan (bucket-major) -> scatter bases
//   k_scatter  : LDS cursors; edge_g[pos] = pack{w:32|collow:9|row:19}
//   k_prep     : per-bucket degw (LDS f32 atomics) -> dinv; xs = fp16(dinv*x)
//   k_pull16_b : acc[512][13] LDS; acc_i = sum w*xs_r + xs_i; epilogue
//                h2s_i = dinv*( relu(dinv*acc_i @ W1 + b1) @ W2 )
//   k_pull2_b  : acc[512][3] LDS; out = log_softmax(dinv*(sum+self)+b2)
// Fallback to the R1 atomic-scatter path if ws too small / n too large.
// ---------------------------------------------------------------------------

typedef unsigned long long u64;
typedef unsigned int u32;
typedef _Float16 f16;
typedef __attribute__((ext_vector_type(8))) _Float16 f16x8;

#define BKT    512        // nodes per bucket (collow = 9 bits)
#define NBMAX  1024       // max buckets (=> n <= 2^19, matches row:19 packing)
#define NBLK   512        // partition blocks for count/scatter
#define AST1   13         // acc stride layer1 (11 feats + pad; coprime w/ 32)
#define AST2   3          // acc stride layer2

// ---------------- count / scan / scatter ----------------

__global__ __launch_bounds__(256) void k_count(const int* __restrict__ col,
                                               u32* __restrict__ hist_g,
                                               int NB, int E, int CH) {
    __shared__ u32 cnt[NBMAX];
    for (int b = threadIdx.x; b < NB; b += 256) cnt[b] = 0;
    __syncthreads();
    int blk = blockIdx.x;
    int s = blk * CH, e = min(s + CH, E);
    for (int i = s + threadIdx.x; i < e; i += 256)
        atomicAdd(&cnt[col[i] >> 9], 1u);          // LDS atomic
    __syncthreads();
    for (int b = threadIdx.x; b < NB; b += 256)
        hist_g[(size_t)blk * NB + b] = cnt[b];     // coalesced
}

// logical index e = bucket*NBLK + blk ; physical = blk*NB + bucket
__global__ __launch_bounds__(256) void k_scan_local32(const u32* __restrict__ hist_g,
                                                      u32* __restrict__ base_g,
                                                      u32* __restrict__ bsum,
                                                      int NB, int M) {
    __shared__ u32 s[256];
    int t = threadIdx.x;
    int e = blockIdx.x * 256 + t;
    u32 v = 0;
    if (e < M) {
        int b = e / NBLK, blk = e % NBLK;
        v = hist_g[(size_t)blk * NB + b];
    }
    s[t] = v;
    __syncthreads();
    for (int off = 1; off < 256; off <<= 1) {
        u32 u = (t >= off) ? s[t - off] : 0;
        __syncthreads();
        s[t] += u;
        __syncthreads();
    }
    if (e < M) base_g[e] = s[t] - v;               // exclusive
    if (t == 255) bsum[blockIdx.x] = s[255];
}

__global__ __launch_bounds__(256) void k_scan_sums32(u32* __restrict__ bsum, int nb) {
    __shared__ u32 s[256];
    __shared__ u32 carry;
    int t = threadIdx.x;
    if (t == 0) carry = 0;
    __syncthreads();
    int chunks = (nb + 255) / 256;
    for (int ch = 0; ch < chunks; ch++) {
        int i = ch * 256 + t;
        u32 v = (i < nb) ? bsum[i] : 0;
        s[t] = v;
        __syncthreads();
        for (int off = 1; off < 256; off <<= 1) {
            u32 u = (t >= off) ? s[t - off] : 0;
            __syncthreads();
            s[t] += u;
            __syncthreads();
        }
        u32 incl = s[t];
        u32 my_carry = carry;
        if (i < nb) bsum[i] = incl - v + my_carry;
        __syncthreads();
        if (t == 0) carry = my_carry + s[255];
        __syncthreads();
    }
}

__global__ __launch_bounds__(256) void k_scan_add32(u32* __restrict__ base_g,
                                                    const u32* __restrict__ bsum,
                                                    int M) {
    int e = blockIdx.x * 256 + threadIdx.x;
    if (e < M) base_g[e] += bsum[blockIdx.x];
}

__global__ __launch_bounds__(256) void k_scatter(const int* __restrict__ row,
                                                 const int* __restrict__ col,
                                                 const float* __restrict__ w,
                                                 const u32* __restrict__ base_g,
                                                 u64* __restrict__ edge_g,
                                                 int NB, int E, int CH) {
    __shared__ u32 cursor[NBMAX];
    int blk = blockIdx.x;
    for (int b = threadIdx.x; b < NB; b += 256)
        cursor[b] = base_g[(size_t)b * NBLK + blk];
    __syncthreads();
    int s = blk * CH, e = min(s + CH, E);
    for (int i = s + threadIdx.x; i < e; i += 256) {
        int c = col[i];
        int b = c >> 9;
        u32 pos = atomicAdd(&cursor[b], 1u);       // LDS atomic
        u64 rec = ((u64)__float_as_uint(w[i]) << 32)
                | ((u64)(u32)(c & 511) << 19) | (u64)(u32)row[i];
        edge_g[pos] = rec;
    }
}

// ---------------- prep: deg -> dinv, xs = fp16(dinv * x) ----------------

__global__ __launch_bounds__(256) void k_prep(const u64* __restrict__ edge_g,
                                              const u32* __restrict__ base_g,
                                              const float* __restrict__ x,
                                              float* __restrict__ dinv_g,
                                              f16* __restrict__ xs,
                                              int NB, int n, int E) {
    __shared__ float degw[BKT];
    int b = blockIdx.x;
    for (int j = threadIdx.x; j < BKT; j += 256) degw[j] = 1.0f;  // self-loop
    __syncthreads();
    int s = (int)base_g[(size_t)b * NBLK];
    int e = (b + 1 < NB) ? (int)base_g[(size_t)(b + 1) * NBLK] : E;
    for (int i = s + threadIdx.x; i < e; i += 256) {
        u64 rec = edge_g[i];
        int cl = (int)(((u32)rec >> 19) & 511u);
        float wv = __uint_as_float((u32)(rec >> 32));
        atomicAdd(&degw[cl], wv);                  // LDS f32 atomic
    }
    __syncthreads();
    int node0 = b << 9;
    int nn = min(BKT, n - node0);
    for (int j = threadIdx.x; j < nn; j += 256) {
        int node = node0 + j;
        float dv = rsqrtf(degw[j]);
        dinv_g[node] = dv;
        f16x8 lo, hi;
#pragma unroll
        for (int k = 0; k < 8; k++) lo[k] = (f16)(dv * x[(size_t)node * 11 + k]);
        hi[0] = (f16)(dv * x[(size_t)node * 11 + 8]);
        hi[1] = (f16)(dv * x[(size_t)node * 11 + 9]);
        hi[2] = (f16)(dv * x[(size_t)node * 11 + 10]);
        hi[3] = (f16)0.f; hi[4] = (f16)0.f; hi[5] = (f16)0.f;
        hi[6] = (f16)0.f; hi[7] = (f16)0.f;
        f16x8* dst = (f16x8*)(xs + ((size_t)node << 4));
        dst[0] = lo;
        dst[1] = hi;
    }
}

// ---------------- bucketed pull layers ----------------

__global__ __launch_bounds__(512) void k_pull16_b(const u64* __restrict__ edge_g,
                                                  const u32* __restrict__ base_g,
                                                  const f16* __restrict__ xs,
                                                  const float* __restrict__ dinv_g,
                                                  const float* __restrict__ W1,
                                                  const float* __restrict__ b1,
                                                  const float* __restrict__ W2,
                                                  float* __restrict__ h2s,
                                                  int NB, int n, int E) {
    __shared__ float acc[BKT * AST1];   // 26.6 KB
    __shared__ float sW1[176];
    __shared__ float sb1[16];
    __shared__ float sW2[32];
    for (int t = threadIdx.x; t < 176; t += 512) sW1[t] = W1[t];
    if (threadIdx.x < 16) sb1[threadIdx.x] = b1[threadIdx.x];
    if (threadIdx.x >= 64 && threadIdx.x < 96) sW2[threadIdx.x - 64] = W2[threadIdx.x - 64];
    int b = blockIdx.x;
    int node0 = b << 9;
    int nn = min(BKT, n - node0);
    // init acc with the self term xs[node]
    for (int t = threadIdx.x; t < nn * 11; t += 512) {
        int j = t / 11, k = t - j * 11;
        acc[j * AST1 + k] = (float)xs[((size_t)(node0 + j) << 4) + k];
    }
    __syncthreads();
    int s = (int)base_g[(size_t)b * NBLK];
    int e = (b + 1 < NB) ? (int)base_g[(size_t)(b + 1) * NBLK] : E;
    int i = s + threadIdx.x;
    // batch of 4 edges: 8 gathers issued before the dependent LDS atomics
    for (; i + 1536 < e; i += 2048) {
        u64 r0 = edge_g[i], r1 = edge_g[i + 512], r2 = edge_g[i + 1024], r3 = edge_g[i + 1536];
        const f16x8* p0 = (const f16x8*)(xs + ((size_t)((u32)r0 & 0x7FFFFu) << 4));
        const f16x8* p1 = (const f16x8*)(xs + ((size_t)((u32)r1 & 0x7FFFFu) << 4));
        const f16x8* p2 = (const f16x8*)(xs + ((size_t)((u32)r2 & 0x7FFFFu) << 4));
        const f16x8* p3 = (const f16x8*)(xs + ((size_t)((u32)r3 & 0x7FFFFu) << 4));
        f16x8 a0 = p0[0], b0 = p0[1];
        f16x8 a1 = p1[0], b1v = p1[1];
        f16x8 a2 = p2[0], b2v = p2[1];
        f16x8 a3 = p3[0], b3v = p3[1];
#define PROC(rec, LO, HI) { \
        int cl = (int)(((u32)(rec) >> 19) & 511u); \
        float wv = __uint_as_float((u32)((rec) >> 32)); \
        float* a = acc + cl * AST1; \
        atomicAdd(a + 0,  wv * (float)LO[0]); atomicAdd(a + 1,  wv * (float)LO[1]); \
        atomicAdd(a + 2,  wv * (float)LO[2]); atomicAdd(a + 3,  wv * (float)LO[3]); \
        atomicAdd(a + 4,  wv * (float)LO[4]); atomicAdd(a + 5,  wv * (float)LO[5]); \
        atomicAdd(a + 6,  wv * (float)LO[6]); atomicAdd(a + 7,  wv * (float)LO[7]); \
        atomicAdd(a + 8,  wv * (float)HI[0]); atomicAdd(a + 9,  wv * (float)HI[1]); \
        atomicAdd(a + 10, wv * (float)HI[2]); }
        PROC(r0, a0, b0)
        PROC(r1, a1, b1v)
        PROC(r2, a2, b2v)
        PROC(r3, a3, b3v)
    }
    for (; i < e; i += 512) {
        u64 r0 = edge_g[i];
        const f16x8* p0 = (const f16x8*)(xs + ((size_t)((u32)r0 & 0x7FFFFu) << 4));
        f16x8 a0 = p0[0], b0 = p0[1];
        PROC(r0, a0, b0)
    }
#undef PROC
    __syncthreads();
    // epilogue: h2s = dv * ( relu(dv*acc @ W1 + b1) @ W2 )
    for (int j = threadIdx.x; j < nn; j += 512) {
        int node = node0 + j;
        float dv = dinv_g[node];
        float v[11];
#pragma unroll
        for (int k = 0; k < 11; k++) v[k] = dv * acc[j * AST1 + k];
        float o0 = 0.f, o1 = 0.f;
#pragma unroll
        for (int f = 0; f < 16; f++) {
            float h = sb1[f];
#pragma unroll
            for (int k = 0; k < 11; k++) h += v[k] * sW1[k * 16 + f];
            h = fmaxf(h, 0.f);
            o0 += h * sW2[f * 2 + 0];
            o1 += h * sW2[f * 2 + 1];
        }
        float2 ov; ov.x = dv * o0; ov.y = dv * o1;   // h2s = dinv * h2
        *(float2*)(h2s + ((size_t)node << 1)) = ov;
    }
}

__global__ __launch_bounds__(256) void k_pull2_b(const u64* __restrict__ edge_g,
                                                 const u32* __restrict__ base_g,
                                                 const float* __restrict__ h2s,
                                                 const float* __restrict__ dinv_g,
                                                 const float* __restrict__ b2,
                                                 float* __restrict__ out,
                                                 int NB, int n, int E) {
    __shared__ float acc[BKT * AST2];   // 6 KB
    int b = blockIdx.x;
    int node0 = b << 9;
    int nn = min(BKT, n - node0);
    for (int t = threadIdx.x; t < nn * 2; t += 256) {
        int j = t >> 1, f = t & 1;
        acc[j * AST2 + f] = h2s[(size_t)node0 * 2 + t];   // init with self term
    }
    __syncthreads();
    int s = (int)base_g[(size_t)b * NBLK];
    int e = (b + 1 < NB) ? (int)base_g[(size_t)(b + 1) * NBLK] : E;
#pragma unroll 4
    for (int i = s + threadIdx.x; i < e; i += 256) {
        u64 rec = edge_g[i];
        int r  = (int)((u32)rec & 0x7FFFFu);
        int cl = (int)(((u32)rec >> 19) & 511u);
        float wv = __uint_as_float((u32)(rec >> 32));
        float2 hv = *(const float2*)(h2s + (size_t)r * 2);
        atomicAdd(&acc[cl * AST2 + 0], wv * hv.x);
        atomicAdd(&acc[cl * AST2 + 1], wv * hv.y);
    }
    __syncthreads();
    float c0 = b2[0], c1 = b2[1];
    for (int j = threadIdx.x; j < nn; j += 256) {
        int node = node0 + j;
        float dv = dinv_g[node];
        float v0 = dv * acc[j * AST2 + 0] + c0;
        float v1 = dv * acc[j * AST2 + 1] + c1;
        float m = fmaxf(v0, v1);
        float lse = m + logf(expf(v0 - m) + expf(v1 - m));
        float2 ov; ov.x = v0 - lse; ov.y = v1 - lse;
        *(float2*)(out + (size_t)node * 2) = ov;
    }
}

// ---------------- fallback atomic-scatter kernels (R1 proven path) ----------------

__global__ __launch_bounds__(256) void k_init_deg(float* deg, int n) {
    int i = blockIdx.x * blockDim.x + threadIdx.x;
    if (i < n) deg[i] = 1.0f;
}

__global__ __launch_bounds__(256) void k_deg_accum(const int* __restrict__ col,
                                                   const float* __restrict__ w,
                                                   float* __restrict__ deg, int E) {
    int i = blockIdx.x * blockDim.x + threadIdx.x;
    if (i < E) atomicAdd(&deg[col[i]], w[i]);
}

__global__ __launch_bounds__(256) void k_rsqrt(float* deg, int n) {
    int i = blockIdx.x * blockDim.x + threadIdx.x;
    if (i < n) {
        float d = deg[i];
        deg[i] = (d > 0.0f) ? rsqrtf(d) : 0.0f;
    }
}

__global__ __launch_bounds__(256) void k_gemm1_plain(const float* __restrict__ x,
                                                     const float* __restrict__ W1,
                                                     float* __restrict__ h1, int n) {
    __shared__ float sW[176];
    for (int t = threadIdx.x; t < 176; t += blockDim.x) sW[t] = W1[t];
    __syncthreads();
    int i = blockIdx.x * blockDim.x + threadIdx.x;
    if (i >= n) return;
    float xi[11];
#pragma unroll
    for (int k = 0; k < 11; k++) xi[k] = x[(size_t)i * 11 + k];
#pragma unroll
    for (int f = 0; f < 16; f++) {
        float acc = 0.0f;
#pragma unroll
        for (int k = 0; k < 11; k++) acc += xi[k] * sW[k * 16 + f];
        h1[(size_t)i * 16 + f] = acc;
    }
}

__global__ __launch_bounds__(256) void k_scatter16(const int* __restrict__ row,
                                                   const int* __restrict__ col,
                                                   const float* __restrict__ w,
                                                   const float* __restrict__ dinv,
                                                   const float* __restrict__ h1,
                                                   float* __restrict__ acc, int E) {
    int i = blockIdx.x * blockDim.x + threadIdx.x;
    if (i >= E) return;
    int r = row[i], c = col[i];
    float nw = dinv[r] * w[i] * dinv[c];
    const float4* hr = (const float4*)(h1 + (size_t)r * 16);
    float* o = acc + (size_t)c * 16;
#pragma unroll
    for (int q = 0; q < 4; q++) {
        float4 hv = hr[q];
        atomicAdd(o + q * 4 + 0, nw * hv.x);
        atomicAdd(o + q * 4 + 1, nw * hv.y);
        atomicAdd(o + q * 4 + 2, nw * hv.z);
        atomicAdd(o + q * 4 + 3, nw * hv.w);
    }
}

__global__ __launch_bounds__(256) void k_post1(const float* __restrict__ h1,
                                               const float* __restrict__ dinv,
                                               const float* __restrict__ b1,
                                               float* __restrict__ acc, int n) {
    int i = blockIdx.x * blockDim.x + threadIdx.x;
    if (i >= n) return;
    float dv = dinv[i];
    float cs = dv * dv;
#pragma unroll
    for (int f = 0; f < 16; f++) {
        float v = acc[(size_t)i * 16 + f] + cs * h1[(size_t)i * 16 + f] + b1[f];
        acc[(size_t)i * 16 + f] = v > 0.0f ? v : 0.0f;
    }
}

__global__ __launch_bounds__(256) void k_gemm2(const float* __restrict__ hrelu,
                                               const float* __restrict__ W2,
                                               float* __restrict__ h2, int n) {
    __shared__ float sW[32];
    for (int t = threadIdx.x; t < 32; t += blockDim.x) sW[t] = W2[t];
    __syncthreads();
    int i = blockIdx.x * blockDim.x + threadIdx.x;
    if (i >= n) return;
    float a0 = 0.0f, a1 = 0.0f;
#pragma unroll
    for (int f = 0; f < 16; f++) {
        float h = hrelu[(size_t)i * 16 + f];
        a0 += h * sW[f * 2 + 0];
        a1 += h * sW[f * 2 + 1];
    }
    h2[(size_t)i * 2 + 0] = a0;
    h2[(size_t)i * 2 + 1] = a1;
}

__global__ __launch_bounds__(256) void k_scatter2(const int* __restrict__ row,
                                                  const int* __restrict__ col,
                                                  const float* __restrict__ w,
                                                  const float* __restrict__ dinv,
                                                  const float* __restrict__ h2,
                                                  float* __restrict__ out, int E) {
    int i = blockIdx.x * blockDim.x + threadIdx.x;
    if (i >= E) return;
    int r = row[i], c = col[i];
    float nw = dinv[r] * w[i] * dinv[c];
    atomicAdd(&out[(size_t)c * 2 + 0], nw * h2[(size_t)r * 2 + 0]);
    atomicAdd(&out[(size_t)c * 2 + 1], nw * h2[(size_t)r * 2 + 1]);
}

__global__ __launch_bounds__(256) void k_final(const float* __restrict__ h2,
                                               const float* __restrict__ dinv,
                                               const float* __restrict__ b2,
                                               float* __restrict__ out, int n) {
    int i = blockIdx.x * blockDim.x + threadIdx.x;
    if (i >= n) return;
    float dv = dinv[i];
    float cs = dv * dv;
    float v0 = out[(size_t)i * 2 + 0] + cs * h2[(size_t)i * 2 + 0] + b2[0];
    float v1 = out[(size_t)i * 2 + 1] + cs * h2[(size_t)i * 2 + 1] + b2[1];
    float m = fmaxf(v0, v1);
    float lse = m + logf(expf(v0 - m) + expf(v1 - m));
    out[(size_t)i * 2 + 0] = v0 - lse;
    out[(size_t)i * 2 + 1] = v1 - lse;
}

// ---------------- launch ----------------

static inline size_t align64(size_t x) { return (x + 63) & ~(size_t)63; }

extern "C" void kernel_launch(void* const* d_in, const int* in_sizes, int n_in,
                              void* d_out, int out_size, void* d_ws, size_t ws_size,
                              hipStream_t stream) {
    const float* x  = (const float*)d_in[0];
    const int*   ei = (const int*)d_in[1];
    const float* ew = (const float*)d_in[2];
    const float* W1 = (const float*)d_in[3];
    const float* b1 = (const float*)d_in[4];
    const float* W2 = (const float*)d_in[5];
    const float* b2 = (const float*)d_in[6];

    const int n = in_sizes[0] / 11;
    const int E = in_sizes[2];
    const int* rowp = ei;       // sources
    const int* colp = ei + E;   // targets

    const int TB = 256;
    const int gN = (n + TB - 1) / TB;
    const int gE = (E + TB - 1) / TB;

    const int NB = (n + BKT - 1) / BKT;            // buckets
    const int CH = (E + NBLK - 1) / NBLK;          // edges per partition block
    const int M  = NB * NBLK;                      // scan length
    const int SB = (M + 255) / 256;                // scan blocks

    // --- workspace layout (bucketed path) ---
    char* base = (char*)d_ws;
    size_t o_hist = 0;                                        // u32 M
    size_t o_base = align64(o_hist + (size_t)M * 4);          // u32 M
    size_t o_bsum = align64(o_base + (size_t)M * 4);          // u32 SB
    size_t o_dinv = align64(o_bsum + (size_t)SB * 4);         // f32 n
    size_t o_xs   = align64(o_dinv + (size_t)n * 4);          // f16 16n (32B rows)
    size_t o_h2   = align64(o_xs + (size_t)n * 16 * 2);       // f32 2n
    size_t o_edge = align64(o_h2 + (size_t)n * 2 * 4);        // u64 E
    size_t needed = align64(o_edge + (size_t)E * 8);

    float* outf = (float*)d_out;

    if (ws_size >= needed && n <= (1 << 19) && NB <= NBMAX) {
        u32*   hist_g = (u32*)(base + o_hist);
        u32*   base_g = (u32*)(base + o_base);
        u32*   bsum   = (u32*)(base + o_bsum);
        float* dinv_g = (float*)(base + o_dinv);
        f16*   xs     = (f16*)(base + o_xs);
        float* h2s    = (float*)(base + o_h2);
        u64*   edge_g = (u64*)(base + o_edge);

        k_count<<<NBLK, TB, 0, stream>>>(colp, hist_g, NB, E, CH);
        k_scan_local32<<<SB, TB, 0, stream>>>(hist_g, base_g, bsum, NB, M);
        k_scan_sums32<<<1, TB, 0, stream>>>(bsum, SB);
        k_scan_add32<<<SB, TB, 0, stream>>>(base_g, bsum, M);
        k_scatter<<<NBLK, TB, 0, stream>>>(rowp, colp, ew, base_g, edge_g, NB, E, CH);
        k_prep<<<NB, TB, 0, stream>>>(edge_g, base_g, x, dinv_g, xs, NB, n, E);
        k_pull16_b<<<NB, 512, 0, stream>>>(edge_g, base_g, xs, dinv_g, W1, b1, W2, h2s, NB, n, E);
        k_pull2_b<<<NB, TB, 0, stream>>>(edge_g, base_g, h2s, dinv_g, b2, outf, NB, n, E);
    } else {
        // fallback: atomic-scatter path (R1)
        float* ws   = (float*)d_ws;
        float* dinv = ws;
        float* h1   = ws + (size_t)n;
        float* acc1 = ws + (size_t)n * 17;

        k_init_deg<<<gN, TB, 0, stream>>>(dinv, n);
        k_deg_accum<<<gE, TB, 0, stream>>>(colp, ew, dinv, E);
        k_rsqrt<<<gN, TB, 0, stream>>>(dinv, n);

        k_gemm1_plain<<<gN, TB, 0, stream>>>(x, W1, h1, n);
        hipMemsetAsync(acc1, 0, (size_t)n * 16 * sizeof(float), stream);
        k_scatter16<<<gE, TB, 0, stream>>>(rowp, colp, ew, dinv, h1, acc1, E);
        k_post1<<<gN, TB, 0, stream>>>(h1, dinv, b1, acc1, n);

        float* h2 = h1;
        k_gemm2<<<gN, TB, 0, stream>>>(acc1, W2, h2, n);
        hipMemsetAsync(outf, 0, (size_t)n * 2 * sizeof(float), stream);
        k_scatter2<<<gE, TB, 0, stream>>>(rowp, colp, ew, dinv, h2, outf, E);
        k_final<<<gN, TB, 0, stream>>>(h2, dinv, b2, outf, n);
    }
}